// Round 12
// baseline (281.900 us; speedup 1.0000x reference)
//
#include <hip/hip_runtime.h>
#include <hip/hip_bf16.h>

// NLM_7962869366897: fused per-feature GLU-MLP, three-kernel pipeline.
// A1: transpose st  [B][D][M] f32 -> stT [D][B][M] bf16  (contiguous per-d panels)
// A2: transpose w1a -> wsA [D][128][32] bf16; w1b -> wsB [D][128] f32
// B : per-d GEMM [512x32]@[32x128] via mfma_f32_16x16x32_bf16; all reads stream.

#define NB 512
#define ND 2048
#define NM 32
#define NH2 128  // 2H

typedef __bf16 bf16x8 __attribute__((ext_vector_type(8)));
typedef float f32x4 __attribute__((ext_vector_type(4)));
typedef float f32x2 __attribute__((ext_vector_type(2)));

#define WSA_BYTES ((size_t)ND * NH2 * NM * 2)          // 16.8 MB
#define WSB_BYTES ((size_t)ND * NH2 * 4)               // 1.05 MB
// stT at WSA_BYTES + WSB_BYTES: 2048*512*32*2 = 67.1 MB

__device__ __forceinline__ float sigmoid_fast(float x) {
    return __builtin_amdgcn_rcpf(1.0f + __builtin_amdgcn_exp2f(-1.442695040888963f * x));
}

// ---------------- A1: state transpose ----------------
// block = 8 d x 64 b. read st rows contiguous (1KB per b-row); write stT rows
// contiguous (4KB per d-row, half-wave 2KB spans). LDS [64][260] f32 (~66.6KB).
__global__ __launch_bounds__(256) void transpose_st(const float* __restrict__ st,
                                                    __bf16* __restrict__ stT) {
    __shared__ float t[64 * 260];
    const int tid = threadIdx.x;
    const int d0 = (int)(blockIdx.x >> 3) * 8;
    const int b0 = (int)(blockIdx.x & 7) * 64;
    // read: thread (r=tid>>2, c=tid&3) covers floats [c*64, c*64+64) of row r's 1KB
    {
        const int r = tid >> 2, c = tid & 3;
        const float* src = st + (size_t)(b0 + r) * (ND * NM) + (size_t)d0 * NM + c * 64;
        #pragma unroll
        for (int i = 0; i < 16; ++i) {
            f32x4 v = *(const f32x4*)(src + i * 4);
            *(f32x4*)&t[r * 260 + c * 65 + i * 4] = v;  // col' = (off>>6)*65 + (off&63)
        }
    }
    __syncthreads();
    // write: thread (dd=tid>>5, l=tid&31); b = l + 32*bb -> contiguous 2KB per half-wave
    {
        const int dd = tid >> 5, l = tid & 31;
        #pragma unroll
        for (int bb = 0; bb < 2; ++bb) {
            const int b = l + 32 * bb;
            #pragma unroll
            for (int ms = 0; ms < 4; ++ms) {
                bf16x8 u;
                #pragma unroll
                for (int i = 0; i < 8; ++i) {
                    const int o = dd * 32 + ms * 8 + i;          // (d-local)*32 + m
                    u[i] = (__bf16)t[b * 260 + (o >> 6) * 65 + (o & 63)];
                }
                *(bf16x8*)(stT + (size_t)(d0 + dd) * (NB * NM)
                               + (size_t)(b0 + b) * NM + ms * 8) = u;
            }
        }
    }
}

// ---------------- A2: weight transpose (unchanged) ----------------
__global__ __launch_bounds__(256) void transpose_w(const float* __restrict__ w1a,
                                                   const float* __restrict__ w1b,
                                                   __bf16* __restrict__ wsA,
                                                   float* __restrict__ wsB) {
    __shared__ float tile[64 * 65];
    const int tid = threadIdx.x;
    if (blockIdx.x < 2048) {
        const int h0 = (blockIdx.x & 63) * 2;
        const int d0 = (blockIdx.x >> 6) * 64;
        const int dc = tid & 63, wv = tid >> 6;
        #pragma unroll
        for (int k = 0; k < 16; ++k) {
            const int rr = wv + 4 * k;
            const int m = rr >> 1, hh = rr & 1;
            tile[rr * 65 + dc] = w1a[(size_t)(m * 128 + h0 + hh) * ND + d0 + dc];
        }
        __syncthreads();
        const int dloc = tid >> 2, seg = tid & 3;
        bf16x8 u0, u1;
        #pragma unroll
        for (int i = 0; i < 8; ++i) {
            const int q0 = seg * 16 + i;        // q' = hh*32 + m
            u0[i] = (__bf16)tile[((q0 & 31) * 2 + (q0 >> 5)) * 65 + dloc];
            const int q1 = seg * 16 + 8 + i;
            u1[i] = (__bf16)tile[((q1 & 31) * 2 + (q1 >> 5)) * 65 + dloc];
        }
        __bf16* dst = wsA + (size_t)(d0 + dloc) * (NH2 * NM) + h0 * 32 + seg * 16;
        *(bf16x8*)dst = u0;
        *(bf16x8*)(dst + 8) = u1;
    } else {
        const int d0 = (blockIdx.x - 2048) * 16;
        const int dcol = tid & 15, pr = tid >> 4;
        #pragma unroll
        for (int k = 0; k < 8; ++k) {
            const int p = pr + 16 * k;
            tile[p * 17 + dcol] = w1b[(size_t)p * ND + d0 + dcol];
        }
        __syncthreads();
        const int dloc = tid >> 4, j = tid & 15;
        #pragma unroll
        for (int i = 0; i < 8; ++i) {
            const int row = j * 8 + i;
            wsB[(size_t)(d0 + dloc) * 128 + j * 8 + i] = tile[row * 17 + dloc];
        }
    }
}

// ---------------- B: fused compute, all-streaming ----------------
__global__ __launch_bounds__(256) void nlm_fused(
    const __bf16* __restrict__ stT,  // [D][B][M] bf16
    const __bf16* __restrict__ wsA,  // [D][128][32] bf16
    const float*  __restrict__ b1a,  // [1, D, 2H]
    const float*  __restrict__ Ta,
    const float*  __restrict__ wsB,  // [D][128] f32 (h*2+c)
    const float*  __restrict__ b1b,  // [1, D, 2]
    const float*  __restrict__ Tb,
    float*        __restrict__ out)  // [B, D]
{
    const int bid  = blockIdx.x;
    // XCD-chunked: consecutive d on the same XCD -> out-line write combining in L2
    const int d    = (bid & 7) * (ND / 8) + (bid >> 3);
    const int tid  = threadIdx.x;
    const int wave = tid >> 6;
    const int lane = tid & 63;
    const int l15  = lane & 15;
    const int lg   = lane >> 4;     // 0..3

    const int bbase = wave * 128;
    const __bf16* sd = stT + (size_t)d * (NB * NM) + (size_t)(bbase + l15) * NM + lg * 8;
    // state tiles: ONE 16B load per tile; lanes cover 1KB contiguous. depth-4 pipeline.
    bf16x8 p[4];
    #pragma unroll
    for (int i = 0; i < 4; ++i)
        p[i] = *(const bf16x8*)(sd + (size_t)i * 16 * NM);

    // weights/bias (L2/L3-hot, reused all 8 tiles)
    const __bf16* wA = wsA + (size_t)d * (NH2 * NM);
    bf16x8 afrag[8];
    #pragma unroll
    for (int t = 0; t < 8; ++t)
        afrag[t] = *(const bf16x8*)(wA + (t * 16 + l15) * 32 + lg * 8);

    f32x4 bias[8];
    #pragma unroll
    for (int t = 0; t < 8; ++t)
        bias[t] = *(const f32x4*)(b1a + (size_t)d * 128 + t * 16 + lg * 4);

    const float* w2d = wsB + (size_t)d * 128;
    float w2a[4][4], w2b[4][4];
    #pragma unroll
    for (int t = 0; t < 4; ++t)
        #pragma unroll
        for (int r = 0; r < 4; ++r) {
            const int h = t * 16 + lg * 4 + r;
            f32x2 q = *(const f32x2*)(w2d + h * 2);
            w2a[t][r] = q[0];
            w2b[t][r] = q[1];
        }

    const float rTa = 1.0f / Ta[0];
    const float rTb = 1.0f / Tb[0];
    const float bb0 = b1b[d * 2 + 0];
    const float bb1 = b1b[d * 2 + 1];

    #pragma unroll
    for (int bt = 0; bt < 8; ++bt) {
        const bf16x8 bfrag = p[bt & 3];
        if (bt < 4)  // refill slot with tile bt+4 (static index under full unroll)
            p[bt & 3] = *(const bf16x8*)(sd + (size_t)(bt + 4) * 16 * NM);

        f32x4 acc[8];
        #pragma unroll
        for (int t = 0; t < 8; ++t) acc[t] = bias[t];
        #pragma unroll
        for (int t = 0; t < 8; ++t)
            acc[t] = __builtin_amdgcn_mfma_f32_16x16x32_bf16(afrag[t], bfrag, acc[t], 0, 0, 0);

        // GLU pairs (h, h+64) = tiles (t, t+4), same reg r; lane holds batch l15.
        float z0 = 0.0f, z1 = 0.0f;
        #pragma unroll
        for (int t = 0; t < 4; ++t)
            #pragma unroll
            for (int r = 0; r < 4; ++r) {
                const float ya = acc[t][r]     * rTa;
                const float yb = acc[t + 4][r] * rTa;
                const float g  = ya * sigmoid_fast(yb);
                z0 = fmaf(g, w2a[t][r], z0);
                z1 = fmaf(g, w2b[t][r], z1);
            }
        z0 += __shfl_xor(z0, 16);
        z0 += __shfl_xor(z0, 32);
        z1 += __shfl_xor(z1, 16);
        z1 += __shfl_xor(z1, 32);
        if (lg == 0) {
            const float za = (z0 + bb0) * rTb;
            const float zb = (z1 + bb1) * rTb;
            out[(size_t)(bbase + bt * 16 + l15) * ND + d] = za * sigmoid_fast(zb);
        }
    }
}

extern "C" void kernel_launch(void* const* d_in, const int* in_sizes, int n_in,
                              void* d_out, int out_size, void* d_ws, size_t ws_size,
                              hipStream_t stream) {
    const float* st  = (const float*)d_in[0];
    const float* w1a = (const float*)d_in[1];
    const float* b1a = (const float*)d_in[2];
    const float* Ta  = (const float*)d_in[3];
    const float* w1b = (const float*)d_in[4];
    const float* b1b = (const float*)d_in[5];
    const float* Tb  = (const float*)d_in[6];
    float* out = (float*)d_out;

    __bf16* wsA = (__bf16*)d_ws;
    float*  wsB = (float*)((char*)d_ws + WSA_BYTES);
    __bf16* stT = (__bf16*)((char*)d_ws + WSA_BYTES + WSB_BYTES);

    transpose_st<<<dim3(2048), dim3(256), 0, stream>>>(st, stT);
    transpose_w<<<dim3(2048 + 128), dim3(256), 0, stream>>>(w1a, w1b, wsA, wsB);
    nlm_fused<<<dim3(ND), dim3(256), 0, stream>>>(stT, wsA, b1a, Ta, wsB, b1b, Tb, out);
}

// Round 13
// 268.935 us; speedup vs baseline: 1.0482x; 1.0482x over previous
//
#include <hip/hip_runtime.h>
#include <hip/hip_bf16.h>

// NLM_7962869366897: fused per-feature GLU-MLP.
// transpose_w: w1a -> wsA [D][128][32] bf16; w1b -> wsB [D][128] f32 (reused operands only)
// nlm_fused:  block = 64 batches x 8 d. st read in NATIVE layout (1KB contiguous
//             runs), staged to LDS as bf16. Per d: 8x mfma_f32_16x16x32_bf16,
//             GLU+layer2 epilogue, out staged in LDS -> contiguous 32B row writes.

#define NB 512
#define ND 2048
#define NM 32
#define NH2 128   // 2H
#define DCHUNK 8
#define BTILE 64

typedef __bf16 bf16x8 __attribute__((ext_vector_type(8)));
typedef __bf16 bf16x4 __attribute__((ext_vector_type(4)));
typedef float f32x4 __attribute__((ext_vector_type(4)));
typedef float f32x2 __attribute__((ext_vector_type(2)));

#define WSA_BYTES ((size_t)ND * NH2 * NM * 2)   // 16.8 MB

__device__ __forceinline__ float sigmoid_fast(float x) {
    return __builtin_amdgcn_rcpf(1.0f + __builtin_amdgcn_exp2f(-1.442695040888963f * x));
}

// ---------------- weight transpose (unchanged, verified r10) ----------------
__global__ __launch_bounds__(256) void transpose_w(const float* __restrict__ w1a,
                                                   const float* __restrict__ w1b,
                                                   __bf16* __restrict__ wsA,
                                                   float* __restrict__ wsB) {
    __shared__ float tile[64 * 65];
    const int tid = threadIdx.x;
    if (blockIdx.x < 2048) {
        const int h0 = (blockIdx.x & 63) * 2;
        const int d0 = (blockIdx.x >> 6) * 64;
        const int dc = tid & 63, wv = tid >> 6;
        #pragma unroll
        for (int k = 0; k < 16; ++k) {
            const int rr = wv + 4 * k;
            const int m = rr >> 1, hh = rr & 1;
            tile[rr * 65 + dc] = w1a[(size_t)(m * 128 + h0 + hh) * ND + d0 + dc];
        }
        __syncthreads();
        const int dloc = tid >> 2, seg = tid & 3;
        bf16x8 u0, u1;
        #pragma unroll
        for (int i = 0; i < 8; ++i) {
            const int q0 = seg * 16 + i;        // q' = hh*32 + m
            u0[i] = (__bf16)tile[((q0 & 31) * 2 + (q0 >> 5)) * 65 + dloc];
            const int q1 = seg * 16 + 8 + i;
            u1[i] = (__bf16)tile[((q1 & 31) * 2 + (q1 >> 5)) * 65 + dloc];
        }
        __bf16* dst = wsA + (size_t)(d0 + dloc) * (NH2 * NM) + h0 * 32 + seg * 16;
        *(bf16x8*)dst = u0;
        *(bf16x8*)(dst + 8) = u1;
    } else {
        const int d0 = (blockIdx.x - 2048) * 16;
        const int dcol = tid & 15, pr = tid >> 4;
        #pragma unroll
        for (int k = 0; k < 8; ++k) {
            const int p = pr + 16 * k;
            tile[p * 17 + dcol] = w1b[(size_t)p * ND + d0 + dcol];
        }
        __syncthreads();
        const int dloc = tid >> 4, j = tid & 15;
        #pragma unroll
        for (int i = 0; i < 8; ++i) {
            const int row = j * 8 + i;
            wsB[(size_t)(d0 + dloc) * 128 + j * 8 + i] = tile[row * 17 + dloc];
        }
    }
}

// ---------------- fused compute: 64 b x 8 d per block ----------------
__global__ __launch_bounds__(256) void nlm_fused(
    const float*  __restrict__ st,   // [B, D, M] f32 (native)
    const __bf16* __restrict__ wsA,  // [D][128][32] bf16
    const float*  __restrict__ b1a,  // [1, D, 2H]
    const float*  __restrict__ Ta,
    const float*  __restrict__ wsB,  // [D][128] f32 (h*2+c)
    const float*  __restrict__ b1b,  // [1, D, 2]
    const float*  __restrict__ Tb,
    float*        __restrict__ out)  // [B, D]
{
    __shared__ __bf16 sst[BTILE][DCHUNK * NM + 4];  // 64 x 260 bf16, pad breaks bank alias
    __shared__ float  sout[BTILE][DCHUNK + 2];      // 64 x 10 f32

    // grid = 2048: xcd = bid&7 owns dchunks [32*xcd, 32*xcd+32) -> consecutive d
    // on one XCD (L2 write-merge of out lines + wsA slice 2MB L2-resident).
    const int bid    = blockIdx.x;
    const int local  = bid >> 3;
    const int dchunk = (bid & 7) * 32 + (local & 31);
    const int btile  = local >> 5;                  // 0..7
    const int d0 = dchunk * DCHUNK;
    const int b0 = btile * BTILE;

    const int tid  = threadIdx.x;
    const int wave = tid >> 6;
    const int lane = tid & 63;
    const int l15  = lane & 15;
    const int lg   = lane >> 4;     // 0..3

    // ---- stage st -> LDS bf16: 64 b x (8 d x 32 m) ; 1KB-contiguous runs ----
    {
        const float* base = st + (size_t)b0 * (ND * NM) + (size_t)d0 * NM;
        #pragma unroll
        for (int i = 0; i < 16; ++i) {
            const int idx = i * 256 + tid;          // f32x4 unit
            const int b   = idx >> 6;               // 64 units (1KB) per b
            const int off = (idx & 63) * 4;         // f32 index within run
            f32x4 v = *(const f32x4*)(base + (size_t)b * (ND * NM) + off);
            bf16x4 u;
            #pragma unroll
            for (int j = 0; j < 4; ++j) u[j] = (__bf16)v[j];
            *(bf16x4*)&sst[b][off] = u;
        }
    }
    __syncthreads();

    const float rTa = 1.0f / Ta[0];
    const float rTb = 1.0f / Tb[0];
    const int bloc = wave * 16 + l15;               // this lane's batch row (B-frag col)

    // ---- per-d loop: 8 independent small GEMM+epilogue per wave ----
    #pragma unroll
    for (int dd = 0; dd < DCHUNK; ++dd) {
        const int d = d0 + dd;

        // B-fragment: one ds_read_b128
        const bf16x8 bfrag = *(const bf16x8*)&sst[bloc][dd * NM + lg * 8];

        // A-fragments from wsA (L1/L2-hot panel, 1KB-contiguous per t)
        const __bf16* wA = wsA + (size_t)d * (NH2 * NM);
        bf16x8 afrag[8];
        #pragma unroll
        for (int t = 0; t < 8; ++t)
            afrag[t] = *(const bf16x8*)(wA + (t * 16 + l15) * 32 + lg * 8);

        // acc init = b1a (bias folded into C-in)
        f32x4 acc[8];
        #pragma unroll
        for (int t = 0; t < 8; ++t)
            acc[t] = *(const f32x4*)(b1a + (size_t)d * 128 + t * 16 + lg * 4);
        #pragma unroll
        for (int t = 0; t < 8; ++t)
            acc[t] = __builtin_amdgcn_mfma_f32_16x16x32_bf16(afrag[t], bfrag, acc[t], 0, 0, 0);

        // layer-2 weights for this d
        const float* w2d = wsB + (size_t)d * 128;
        // GLU pairs (h, h+64) = acc tiles (t, t+4), same reg r; lane holds b=bloc.
        float z0 = 0.0f, z1 = 0.0f;
        #pragma unroll
        for (int t = 0; t < 4; ++t) {
            const f32x4 wp0 = *(const f32x4*)(w2d + (t * 16 + lg * 4) * 2);
            const f32x4 wp1 = *(const f32x4*)(w2d + (t * 16 + lg * 4) * 2 + 4);
            #pragma unroll
            for (int r = 0; r < 4; ++r) {
                const float ya = acc[t][r]     * rTa;
                const float yb = acc[t + 4][r] * rTa;
                const float g  = ya * sigmoid_fast(yb);
                const float wa = (r < 2) ? wp0[2 * r]     : wp1[2 * (r - 2)];
                const float wb = (r < 2) ? wp0[2 * r + 1] : wp1[2 * (r - 2) + 1];
                z0 = fmaf(g, wa, z0);
                z1 = fmaf(g, wb, z1);
            }
        }
        z0 += __shfl_xor(z0, 16);
        z0 += __shfl_xor(z0, 32);
        z1 += __shfl_xor(z1, 16);
        z1 += __shfl_xor(z1, 32);
        if (lg == 0) {
            const float za = (z0 + b1b[d * 2 + 0]) * rTb;
            const float zb = (z1 + b1b[d * 2 + 1]) * rTb;
            sout[bloc][dd] = za * sigmoid_fast(zb);
        }
    }
    __syncthreads();

    // ---- out write: 32B contiguous per b-row (L2 merges pairs into 64B lines) ----
    if (tid < 128) {
        const int b = tid >> 1, q = (tid & 1) * 4;
        f32x4 v;
        #pragma unroll
        for (int j = 0; j < 4; ++j) v[j] = sout[b][q + j];
        *(f32x4*)(out + (size_t)(b0 + b) * ND + d0 + q) = v;
    }
}

extern "C" void kernel_launch(void* const* d_in, const int* in_sizes, int n_in,
                              void* d_out, int out_size, void* d_ws, size_t ws_size,
                              hipStream_t stream) {
    const float* st  = (const float*)d_in[0];
    const float* w1a = (const float*)d_in[1];
    const float* b1a = (const float*)d_in[2];
    const float* Ta  = (const float*)d_in[3];
    const float* w1b = (const float*)d_in[4];
    const float* b1b = (const float*)d_in[5];
    const float* Tb  = (const float*)d_in[6];
    float* out = (float*)d_out;

    __bf16* wsA = (__bf16*)d_ws;
    float*  wsB = (float*)((char*)d_ws + WSA_BYTES);

    transpose_w<<<dim3(2048 + 128), dim3(256), 0, stream>>>(w1a, w1b, wsA, wsB);
    nlm_fused<<<dim3(2048), dim3(256), 0, stream>>>(st, wsA, b1a, Ta, wsB, b1b, Tb, out);
}

// Round 15
// 267.181 us; speedup vs baseline: 1.0551x; 1.0066x over previous
//
#include <hip/hip_runtime.h>
#include <hip/hip_bf16.h>

// NLM_7962869366897: fused per-feature GLU-MLP.
// transpose_w: w1a -> wsA [D][128][32] bf16; w1b -> wsB [D][128] f32
// nlm_fused:  block = 64 b x 8 d. st staged via explicit 16-reg pipeline (16KB
//             in flight/wave); per-d afrag double-buffered; bias folded post-MFMA.

#define NB 512
#define ND 2048
#define NM 32
#define NH2 128   // 2H
#define DCHUNK 8
#define BTILE 64

typedef __bf16 bf16x8 __attribute__((ext_vector_type(8)));
typedef __bf16 bf16x4 __attribute__((ext_vector_type(4)));
typedef float f32x4 __attribute__((ext_vector_type(4)));
typedef float f32x2 __attribute__((ext_vector_type(2)));

#define WSA_BYTES ((size_t)ND * NH2 * NM * 2)   // 16.8 MB

__device__ __forceinline__ float sigmoid_fast(float x) {
    return __builtin_amdgcn_rcpf(1.0f + __builtin_amdgcn_exp2f(-1.442695040888963f * x));
}

// ---------------- weight transpose (unchanged, verified r10) ----------------
__global__ __launch_bounds__(256) void transpose_w(const float* __restrict__ w1a,
                                                   const float* __restrict__ w1b,
                                                   __bf16* __restrict__ wsA,
                                                   float* __restrict__ wsB) {
    __shared__ float tile[64 * 65];
    const int tid = threadIdx.x;
    if (blockIdx.x < 2048) {
        const int h0 = (blockIdx.x & 63) * 2;
        const int d0 = (blockIdx.x >> 6) * 64;
        const int dc = tid & 63, wv = tid >> 6;
        #pragma unroll
        for (int k = 0; k < 16; ++k) {
            const int rr = wv + 4 * k;
            const int m = rr >> 1, hh = rr & 1;
            tile[rr * 65 + dc] = w1a[(size_t)(m * 128 + h0 + hh) * ND + d0 + dc];
        }
        __syncthreads();
        const int dloc = tid >> 2, seg = tid & 3;
        bf16x8 u0, u1;
        #pragma unroll
        for (int i = 0; i < 8; ++i) {
            const int q0 = seg * 16 + i;        // q' = hh*32 + m
            u0[i] = (__bf16)tile[((q0 & 31) * 2 + (q0 >> 5)) * 65 + dloc];
            const int q1 = seg * 16 + 8 + i;
            u1[i] = (__bf16)tile[((q1 & 31) * 2 + (q1 >> 5)) * 65 + dloc];
        }
        __bf16* dst = wsA + (size_t)(d0 + dloc) * (NH2 * NM) + h0 * 32 + seg * 16;
        *(bf16x8*)dst = u0;
        *(bf16x8*)(dst + 8) = u1;
    } else {
        const int d0 = (blockIdx.x - 2048) * 16;
        const int dcol = tid & 15, pr = tid >> 4;
        #pragma unroll
        for (int k = 0; k < 8; ++k) {
            const int p = pr + 16 * k;
            tile[p * 17 + dcol] = w1b[(size_t)p * ND + d0 + dcol];
        }
        __syncthreads();
        const int dloc = tid >> 4, j = tid & 15;
        #pragma unroll
        for (int i = 0; i < 8; ++i) {
            const int row = j * 8 + i;
            wsB[(size_t)(d0 + dloc) * 128 + j * 8 + i] = tile[row * 17 + dloc];
        }
    }
}

// ---------------- fused compute: 64 b x 8 d per block, deep-ILP ----------------
__global__ __launch_bounds__(256, 3) void nlm_fused(
    const float*  __restrict__ st,   // [B, D, M] f32 (native)
    const __bf16* __restrict__ wsA,  // [D][128][32] bf16
    const float*  __restrict__ b1a,  // [1, D, 2H]
    const float*  __restrict__ Ta,
    const float*  __restrict__ wsB,  // [D][128] f32 (h*2+c)
    const float*  __restrict__ b1b,  // [1, D, 2]
    const float*  __restrict__ Tb,
    float*        __restrict__ out)  // [B, D]
{
    __shared__ __bf16 sst[BTILE][DCHUNK * NM + 4];  // 64 x 260 bf16
    __shared__ float  sout[BTILE][DCHUNK + 2];

    const int bid    = blockIdx.x;
    const int local  = bid >> 3;
    const int dchunk = (bid & 7) * 32 + (local & 31);  // consecutive d -> same XCD
    const int btile  = local >> 5;
    const int d0 = dchunk * DCHUNK;
    const int b0 = btile * BTILE;

    const int tid  = threadIdx.x;
    const int wave = tid >> 6;
    const int lane = tid & 63;
    const int l15  = lane & 15;
    const int lg   = lane >> 4;     // 0..3

    // ---- stage st -> LDS: ALL 16 loads issued before any write (16KB/wave in flight) ----
    const float* base = st + (size_t)b0 * (ND * NM) + (size_t)d0 * NM;
    f32x4 sv[16];
    #pragma unroll
    for (int i = 0; i < 16; ++i) {
        const int idx = i * 256 + tid;          // wave w, iter i -> b = i*4+w, 1KB contiguous
        const int b   = idx >> 6;
        const int off = (idx & 63) * 4;
        sv[i] = *(const f32x4*)(base + (size_t)b * (ND * NM) + off);
    }
    #pragma unroll
    for (int i = 0; i < 16; ++i) {
        const int idx = i * 256 + tid;
        const int b   = idx >> 6;
        const int off = (idx & 63) * 4;
        bf16x4 u;
        #pragma unroll
        for (int j = 0; j < 4; ++j) u[j] = (__bf16)sv[i][j];
        *(bf16x4*)&sst[b][off] = u;
    }
    __syncthreads();

    const float rTa = 1.0f / Ta[0];
    const float rTb = 1.0f / Tb[0];
    const int bloc = wave * 16 + l15;           // this lane's batch row (B-frag col)
    const size_t wstr = (size_t)(NH2 * NM);     // 4096 elems per d-panel
    const __bf16* wAl = wsA + l15 * 32 + lg * 8;

    // prefetch afrag for dd=0
    bf16x8 afA[8], afB[8];
    {
        const __bf16* p = wAl + (size_t)d0 * wstr;
        #pragma unroll
        for (int t = 0; t < 8; ++t) afA[t] = *(const bf16x8*)(p + t * 512);
    }

    auto step = [&](int dd, bf16x8 (&afC)[8], bf16x8 (&afN)[8]) {
        const int d = d0 + dd;
        // issue next-d afrag prefetch first (hides L2 latency under this d's compute)
        if (dd < 7) {
            const __bf16* p = wAl + (size_t)(d + 1) * wstr;
            #pragma unroll
            for (int t = 0; t < 8; ++t) afN[t] = *(const bf16x8*)(p + t * 512);
        }
        // bias (pre-scaled) issued before MFMA, consumed after -> latency hidden
        f32x4 biP[8];
        #pragma unroll
        for (int t = 0; t < 8; ++t)
            biP[t] = *(const f32x4*)(b1a + (size_t)d * 128 + t * 16 + lg * 4);
        #pragma unroll
        for (int t = 0; t < 8; ++t)
            #pragma unroll
            for (int r = 0; r < 4; ++r) biP[t][r] *= rTa;

        const bf16x8 bfrag = *(const bf16x8*)&sst[bloc][dd * NM + lg * 8];
        f32x4 acc[8];
        #pragma unroll
        for (int t = 0; t < 8; ++t) acc[t] = (f32x4){0.f, 0.f, 0.f, 0.f};
        #pragma unroll
        for (int t = 0; t < 8; ++t)
            acc[t] = __builtin_amdgcn_mfma_f32_16x16x32_bf16(afC[t], bfrag, acc[t], 0, 0, 0);

        const float* w2d = wsB + (size_t)d * 128;
        float z0 = 0.0f, z1 = 0.0f;
        #pragma unroll
        for (int t = 0; t < 4; ++t) {
            const f32x4 wp0 = *(const f32x4*)(w2d + (t * 16 + lg * 4) * 2);
            const f32x4 wp1 = *(const f32x4*)(w2d + (t * 16 + lg * 4) * 2 + 4);
            #pragma unroll
            for (int r = 0; r < 4; ++r) {
                const float ya = fmaf(acc[t][r],     rTa, biP[t][r]);
                const float yb = fmaf(acc[t + 4][r], rTa, biP[t + 4][r]);
                const float g  = ya * sigmoid_fast(yb);
                const float wa = (r < 2) ? wp0[2 * r]     : wp1[2 * (r - 2)];
                const float wb = (r < 2) ? wp0[2 * r + 1] : wp1[2 * (r - 2) + 1];
                z0 = fmaf(g, wa, z0);
                z1 = fmaf(g, wb, z1);
            }
        }
        z0 += __shfl_xor(z0, 16);
        z0 += __shfl_xor(z0, 32);
        z1 += __shfl_xor(z1, 16);
        z1 += __shfl_xor(z1, 32);
        if (lg == 0) {
            const float za = (z0 + b1b[d * 2 + 0]) * rTb;
            const float zb = (z1 + b1b[d * 2 + 1]) * rTb;
            sout[bloc][dd] = za * sigmoid_fast(zb);
        }
    };
    step(0, afA, afB); step(1, afB, afA); step(2, afA, afB); step(3, afB, afA);
    step(4, afA, afB); step(5, afB, afA); step(6, afA, afB); step(7, afB, afA);

    __syncthreads();

    // out write: 32B contiguous per b-row; XCD-chunked d -> L2 merges into 64B lines
    if (tid < 128) {
        const int b = tid >> 1, q = (tid & 1) * 4;
        f32x4 v;
        #pragma unroll
        for (int j = 0; j < 4; ++j) v[j] = sout[b][q + j];
        *(f32x4*)(out + (size_t)(b0 + b) * ND + d0 + q) = v;
    }
}

extern "C" void kernel_launch(void* const* d_in, const int* in_sizes, int n_in,
                              void* d_out, int out_size, void* d_ws, size_t ws_size,
                              hipStream_t stream) {
    const float* st  = (const float*)d_in[0];
    const float* w1a = (const float*)d_in[1];
    const float* b1a = (const float*)d_in[2];
    const float* Ta  = (const float*)d_in[3];
    const float* w1b = (const float*)d_in[4];
    const float* b1b = (const float*)d_in[5];
    const float* Tb  = (const float*)d_in[6];
    float* out = (float*)d_out;

    __bf16* wsA = (__bf16*)d_ws;
    float*  wsB = (float*)((char*)d_ws + WSA_BYTES);

    transpose_w<<<dim3(2048 + 128), dim3(256), 0, stream>>>(w1a, w1b, wsA, wsB);
    nlm_fused<<<dim3(2048), dim3(256), 0, stream>>>(st, wsA, b1a, Ta, wsB, b1b, Tb, out);
}